// Round 1
// baseline (78.495 us; speedup 1.0000x reference)
//
#include <hip/hip_runtime.h>

#define BOARD 19
#define HW    361            // 19*19
#define NC    256
#define CHUNK 32             // channels staged per LDS chunk
#define NTH   384            // 6 waves
#define F4_PER_CHUNK ((CHUNK * HW) / 4)   // 2888 float4s = 45.1 KB

__global__ __launch_bounds__(NTH)
void output_layer_kernel(const float* __restrict__ x,
                         const float* __restrict__ w,
                         const float* __restrict__ bias,
                         float* __restrict__ out)
{
    __shared__ float4 lds4[F4_PER_CHUNK];   // 46208 B
    __shared__ float  wsh[NC];              // 1024 B
    float* lds = reinterpret_cast<float*>(lds4);

    const int b = blockIdx.x;
    const int t = threadIdx.x;

    if (t < NC) wsh[t] = w[t];

    // Batch base: b * 256*361 floats = b * 92416; divisible by 4 -> float4-aligned.
    const float4* xb = reinterpret_cast<const float4*>(x) + (size_t)b * (NC * HW / 4);

    float acc = 0.0f;
    for (int c0 = 0; c0 < NC; c0 += CHUNK) {
        // c0*361 divisible by 4 for c0 % 4 == 0 -> chunk base is float4-aligned.
        const float4* src = xb + (c0 * HW) / 4;
        #pragma unroll
        for (int i = 0; i < 8; ++i) {
            int k = t + i * NTH;
            if (k < F4_PER_CHUNK) lds4[k] = src[k];
        }
        __syncthreads();
        if (t < HW) {
            #pragma unroll
            for (int cc = 0; cc < CHUNK; ++cc)
                acc = fmaf(lds[cc * HW + t], wsh[c0 + cc], acc);
        }
        __syncthreads();
    }

    if (t < HW) {
        // Analytic reconstruction of build_bias_map():
        // representatives are scanned row-major; orbit of (i,j) folds to the
        // 0..9 quadrant, canonical (r,c) = (min,max) of the folded coords.
        // Row 0: counter = c for c=1..9; corners (0,0) get re-assigned 10
        // (the scan revisits (0,18) because orbit 0 left m==0).
        // Row r>=1: counter = 11 + (r-1)*10 - r*(r-1)/2 + (c - r).
        // Final idx = (counter - 1) % 55.
        const int i = t / BOARD;
        const int j = t % BOARD;
        const int a  = min(i, 18 - i);
        const int bq = min(j, 18 - j);
        const int r  = min(a, bq);
        const int c  = max(a, bq);
        int counter;
        if (r == 0) counter = (c == 0) ? 10 : c;
        else        counter = 11 + (r - 1) * 10 - (r * (r - 1)) / 2 + (c - r);
        const int idx = (counter - 1) % 55;

        out[(size_t)b * HW + t] = acc + bias[idx];
    }
}

extern "C" void kernel_launch(void* const* d_in, const int* in_sizes, int n_in,
                              void* d_out, int out_size, void* d_ws, size_t ws_size,
                              hipStream_t stream)
{
    const float* x    = (const float*)d_in[0];   // (1024, 256, 19, 19) fp32
    const float* w    = (const float*)d_in[1];   // (1, 256, 1, 1) fp32
    const float* bias = (const float*)d_in[2];   // (55,) fp32
    float*       out  = (float*)d_out;           // (1024, 361) fp32

    const int B = in_sizes[0] / (NC * HW);       // 1024
    hipLaunchKernelGGL(output_layer_kernel, dim3(B), dim3(NTH), 0, stream,
                       x, w, bias, out);
}

// Round 2
// 73.689 us; speedup vs baseline: 1.0652x; 1.0652x over previous
//
#include <hip/hip_runtime.h>

#define BOARD 19
#define HW    361            // 19*19
#define NC    256
#define NTH   256

// One thread per output element (b, hw). For fixed channel c, consecutive
// lanes read consecutive global addresses -> fully coalesced dword loads.
// No LDS, no barriers, no idle threads; x is read exactly once.
__global__ __launch_bounds__(NTH)
void output_layer_kernel(const float* __restrict__ x,
                         const float* __restrict__ w,
                         const float* __restrict__ bias,
                         float* __restrict__ out,
                         int total)
{
    const int tid = blockIdx.x * NTH + threadIdx.x;
    if (tid >= total) return;

    const int b  = tid / HW;           // magic-mul div by constant
    const int hw = tid - b * HW;

    const float* __restrict__ xp = x + (size_t)b * (NC * HW) + hw;

    // 4 independent accumulators: breaks the serial FMA chain, and the
    // 16-deep unroll keeps ~16 dword loads in flight per thread.
    float a0 = 0.f, a1 = 0.f, a2 = 0.f, a3 = 0.f;
    #pragma unroll 4
    for (int c = 0; c < NC; c += 16) {
        #pragma unroll
        for (int u = 0; u < 16; u += 4) {
            a0 = fmaf(xp[(c + u + 0) * HW], w[c + u + 0], a0);
            a1 = fmaf(xp[(c + u + 1) * HW], w[c + u + 1], a1);
            a2 = fmaf(xp[(c + u + 2) * HW], w[c + u + 2], a2);
            a3 = fmaf(xp[(c + u + 3) * HW], w[c + u + 3], a3);
        }
    }
    const float acc = (a0 + a1) + (a2 + a3);

    // Analytic reconstruction of build_bias_map() (verified R1, absmax 3.9e-3):
    // fold (i,j) into the 0..9 quadrant, canonical (r,c)=(min,max);
    // row 0: counter=c (corner (0,0) -> 10); row r>=1:
    // counter = 11 + (r-1)*10 - r(r-1)/2 + (c-r); idx = (counter-1) % 55.
    const int i  = hw / BOARD;
    const int j  = hw - i * BOARD;
    const int aq = min(i, 18 - i);
    const int bq = min(j, 18 - j);
    const int r  = min(aq, bq);
    const int cq = max(aq, bq);
    int counter;
    if (r == 0) counter = (cq == 0) ? 10 : cq;
    else        counter = 11 + (r - 1) * 10 - (r * (r - 1)) / 2 + (cq - r);
    const int idx = (counter - 1) % 55;

    out[tid] = acc + bias[idx];
}

extern "C" void kernel_launch(void* const* d_in, const int* in_sizes, int n_in,
                              void* d_out, int out_size, void* d_ws, size_t ws_size,
                              hipStream_t stream)
{
    const float* x    = (const float*)d_in[0];   // (1024, 256, 19, 19) fp32
    const float* w    = (const float*)d_in[1];   // (1, 256, 1, 1) fp32
    const float* bias = (const float*)d_in[2];   // (55,) fp32
    float*       out  = (float*)d_out;           // (1024, 361) fp32

    const int total  = out_size;                 // 1024 * 361 = 369664
    const int blocks = (total + NTH - 1) / NTH;  // 1444
    hipLaunchKernelGGL(output_layer_kernel, dim3(blocks), dim3(NTH), 0, stream,
                       x, w, bias, out, total);
}

// Round 3
// 69.799 us; speedup vs baseline: 1.1246x; 1.0557x over previous
//
#include <hip/hip_runtime.h>

#define BOARD 19
#define HW    361            // 19*19
#define NC    256
#define NTH   384            // 6 waves; threads >= 361 idle
#define NITER (NC / 4)       // 64 iterations of 4 channels

// 4*361 = 1444 floats = exactly 4 channels: advancing a flat float4 index by
// 361 keeps each element's hw fixed and advances the channel by 4. So thread
// s owns aligned float4 slot s; element e has FIXED (c_off, hw):
//   c_off = (4s+e)/361 in {0..3},  hw = (4s+e) % 361,  channel = 4i + c_off.
// All loads are aligned dwordx4, wave-contiguous (1 KB/instruction), and the
// block streams its batch strictly sequentially. Weights w[4i..4i+3] are
// wave-uniform (broadcast LDS read). Partials reduce through LDS at the
// identity layout red[4s+e] = red[c_off*361 + hw].
__global__ __launch_bounds__(NTH)
void output_layer_kernel(const float* __restrict__ x,
                         const float* __restrict__ w,
                         const float* __restrict__ bias,
                         float* __restrict__ out)
{
    __shared__ float4 wsh4[NC / 4];   // w[0..255] as 64 float4
    __shared__ float  red[4 * HW];    // 1444 partials

    const int b = blockIdx.x;
    const int t = threadIdx.x;

    if (t < NC) reinterpret_cast<float*>(wsh4)[t] = w[t];
    __syncthreads();

    if (t < HW) {
        const int s  = t;
        const int f0 = 4 * s;
        const int c0 = f0 / HW;                    // 0..3, fixed per thread
        const int c1 = (c0 < 3) ? c0 + 1 : 3;
        const int m  = min(4, (c0 + 1) * HW - f0); // 1..4; m<4 for only 3 threads
        const bool b1 = (1 < m), b2 = (2 < m), b3 = (3 < m);

        const float4* __restrict__ xb =
            reinterpret_cast<const float4*>(x + (size_t)b * (NC * HW)) + s;

        float a0 = 0.f, a1 = 0.f, a2 = 0.f, a3 = 0.f;
        #pragma unroll 4
        for (int i = 0; i < NITER; ++i) {
            const float4 xv = xb[(size_t)i * HW];  // stride 5776 B, sequential per block
            const float4 wv = wsh4[i];             // wave-uniform broadcast
            const float wlo = (c0 == 0) ? wv.x : (c0 == 1) ? wv.y : (c0 == 2) ? wv.z : wv.w;
            const float whi = (c1 == 1) ? wv.y : (c1 == 2) ? wv.z : wv.w;
            a0 = fmaf(xv.x, wlo,            a0);   // e=0 always below boundary
            a1 = fmaf(xv.y, b1 ? wlo : whi, a1);
            a2 = fmaf(xv.z, b2 ? wlo : whi, a2);
            a3 = fmaf(xv.w, b3 ? wlo : whi, a3);
        }
        reinterpret_cast<float4*>(red)[s] = make_float4(a0, a1, a2, a3);
    }
    __syncthreads();

    if (t < HW) {
        const float acc = (red[t] + red[HW + t]) + (red[2 * HW + t] + red[3 * HW + t]);

        // Analytic build_bias_map() (verified R1/R2, absmax 3.9e-3):
        const int i  = t / BOARD;
        const int j  = t - i * BOARD;
        const int aq = min(i, 18 - i);
        const int bq = min(j, 18 - j);
        const int r  = min(aq, bq);
        const int c  = max(aq, bq);
        int counter;
        if (r == 0) counter = (c == 0) ? 10 : c;
        else        counter = 11 + (r - 1) * 10 - (r * (r - 1)) / 2 + (c - r);
        const int idx = (counter - 1) % 55;

        out[(size_t)b * HW + t] = acc + bias[idx];
    }
}

extern "C" void kernel_launch(void* const* d_in, const int* in_sizes, int n_in,
                              void* d_out, int out_size, void* d_ws, size_t ws_size,
                              hipStream_t stream)
{
    const float* x    = (const float*)d_in[0];   // (1024, 256, 19, 19) fp32
    const float* w    = (const float*)d_in[1];   // (1, 256, 1, 1) fp32
    const float* bias = (const float*)d_in[2];   // (55,) fp32
    float*       out  = (float*)d_out;           // (1024, 361) fp32

    const int B = in_sizes[0] / (NC * HW);       // 1024 blocks, one per batch
    hipLaunchKernelGGL(output_layer_kernel, dim3(B), dim3(NTH), 0, stream,
                       x, w, bias, out);
}

// Round 4
// 68.413 us; speedup vs baseline: 1.1474x; 1.0203x over previous
//
#include <hip/hip_runtime.h>

#define BOARD  19
#define HW     361            // 19*19
#define NC     256
#define NTH    384            // 6 waves; threads >= 361 idle in the stream loop
#define NITER  (NC / 4)       // 64 iterations of 4 channels
#define UNROLL 8              // loads in flight per wave (8 KB) — queue depth lever

// 4*361 = 1444 floats = exactly 4 channels: advancing a flat float4 index by
// 361 keeps each element's hw fixed and advances the channel by 4. Thread s
// owns aligned float4 slot s; element e has FIXED (c_off, hw). All loads are
// aligned dwordx4, wave-contiguous; each block streams its batch sequentially.
// R4 change: explicit 8-deep load/compute phase split so 8 wave-loads are
// outstanding before the first s_waitcnt (was ~2-3 with #pragma unroll 4).
__global__ __launch_bounds__(NTH)
void output_layer_kernel(const float* __restrict__ x,
                         const float* __restrict__ w,
                         const float* __restrict__ bias,
                         float* __restrict__ out)
{
    __shared__ float4 wsh4[NC / 4];   // w[0..255] as 64 float4
    __shared__ float  red[4 * HW];    // 1444 partials

    const int b = blockIdx.x;
    const int t = threadIdx.x;

    if (t < NC) reinterpret_cast<float*>(wsh4)[t] = w[t];
    __syncthreads();

    if (t < HW) {
        const int s  = t;
        const int f0 = 4 * s;
        const int c0 = f0 / HW;                    // 0..3, fixed per thread
        const int c1 = (c0 < 3) ? c0 + 1 : 3;
        const int m  = min(4, (c0 + 1) * HW - f0); // 1..4; m<4 for only 3 threads
        const bool b1 = (1 < m), b2 = (2 < m), b3 = (3 < m);

        const float4* __restrict__ xb =
            reinterpret_cast<const float4*>(x + (size_t)b * (NC * HW)) + s;

        float a0 = 0.f, a1 = 0.f, a2 = 0.f, a3 = 0.f;
        for (int i = 0; i < NITER; i += UNROLL) {
            float4 xv[UNROLL];                     // static indices -> stays in VGPRs
            #pragma unroll
            for (int u = 0; u < UNROLL; ++u)
                xv[u] = xb[(size_t)(i + u) * HW];  // 8 loads issued before any wait
            #pragma unroll
            for (int u = 0; u < UNROLL; ++u) {
                const float4 wv = wsh4[i + u];     // wave-uniform broadcast
                const float wlo = (c0 == 0) ? wv.x : (c0 == 1) ? wv.y : (c0 == 2) ? wv.z : wv.w;
                const float whi = (c1 == 1) ? wv.y : (c1 == 2) ? wv.z : wv.w;
                a0 = fmaf(xv[u].x, wlo,            a0);
                a1 = fmaf(xv[u].y, b1 ? wlo : whi, a1);
                a2 = fmaf(xv[u].z, b2 ? wlo : whi, a2);
                a3 = fmaf(xv[u].w, b3 ? wlo : whi, a3);
            }
        }
        reinterpret_cast<float4*>(red)[s] = make_float4(a0, a1, a2, a3);
    }
    __syncthreads();

    if (t < HW) {
        const float acc = (red[t] + red[HW + t]) + (red[2 * HW + t] + red[3 * HW + t]);

        // Analytic build_bias_map() (verified R1-R3, absmax 3.9e-3):
        const int i  = t / BOARD;
        const int j  = t - i * BOARD;
        const int aq = min(i, 18 - i);
        const int bq = min(j, 18 - j);
        const int r  = min(aq, bq);
        const int c  = max(aq, bq);
        int counter;
        if (r == 0) counter = (c == 0) ? 10 : c;
        else        counter = 11 + (r - 1) * 10 - (r * (r - 1)) / 2 + (c - r);
        const int idx = (counter - 1) % 55;

        out[(size_t)b * HW + t] = acc + bias[idx];
    }
}

extern "C" void kernel_launch(void* const* d_in, const int* in_sizes, int n_in,
                              void* d_out, int out_size, void* d_ws, size_t ws_size,
                              hipStream_t stream)
{
    const float* x    = (const float*)d_in[0];   // (1024, 256, 19, 19) fp32
    const float* w    = (const float*)d_in[1];   // (1, 256, 1, 1) fp32
    const float* bias = (const float*)d_in[2];   // (55,) fp32
    float*       out  = (float*)d_out;           // (1024, 361) fp32

    const int B = in_sizes[0] / (NC * HW);       // 1024 blocks, one per batch
    hipLaunchKernelGGL(output_layer_kernel, dim3(B), dim3(NTH), 0, stream,
                       x, w, bias, out);
}